// Round 5
// baseline (4073.705 us; speedup 1.0000x reference)
//
#include <hip/hip_runtime.h>
#include <hip/hip_bf16.h>
#include <math.h>

#define NTAG 96
#define NB   128
#define SLEN 2048
#define CPERB (SLEN * NTAG)     // floats per batch row of em
#define NCH  8                  // chunks per sequence
#define CHUNK 256               // steps per chunk (last chunk: 255)
#define LW   52                 // LDS row stride (dwords): 16B-aligned rows, uniform banks

typedef __attribute__((ext_vector_type(8))) short bf16x8;
typedef __attribute__((ext_vector_type(4))) float f32x4;
union U8 { unsigned int u[4]; bf16x8 v; };

__device__ __forceinline__ unsigned int pk2bf(float lo, float hi) {
    union { __hip_bfloat16 h; unsigned short u; } a, b;
    a.h = __float2bfloat16(lo);
    b.h = __float2bfloat16(hi);
    return (unsigned int)a.u | ((unsigned int)b.u << 16);
}

__device__ __forceinline__ float waveSum(float v) {
    #pragma unroll
    for (int o = 32; o > 0; o >>= 1) v += __shfl_xor(v, o);
    return v;
}

// ---------------------------------------------------------------------------
// exp_pass: eexp[i] = exp(em[i]), f32x4 per thread. Memory-bound.
// ---------------------------------------------------------------------------
__global__ __launch_bounds__(256) void exp_pass(
    const float* __restrict__ x, float* __restrict__ y)
{
    size_t i = (size_t)blockIdx.x * 256 + threadIdx.x;   // one f32x4 each
    f32x4 v = ((const f32x4*)x)[i];
    f32x4 o;
    o[0] = __expf(v[0]); o[1] = __expf(v[1]);
    o[2] = __expf(v[2]); o[3] = __expf(v[3]);
    ((f32x4*)y)[i] = o;
}

// ---------------------------------------------------------------------------
// Phase 1: per (batch, chunk, strip) wave computes a 96x16 column-strip of
// the chunk operator product  M <- diag(e_t) * T^T * M,  M init = Identity.
// IEXP=1: srcE is raw em (exp applied inline). IEXP=0: srcE is eexp.
// ---------------------------------------------------------------------------
template <int IEXP>
__global__ __launch_bounds__(64, 4) void crf_chunk(
    const float* __restrict__ srcE, const float* __restrict__ mask,
    const float* __restrict__ trans,
    float* __restrict__ P, float* __restrict__ Pls)
{
    __shared__ unsigned int lbuf[16 * LW];   // [b16][q], q=0..47
    const int tid = threadIdx.x;
    const int g = tid >> 4, b16 = tid & 15;
    const int wid = blockIdx.x;              // [0, 6*1024)
    const int w  = wid >> 10;                // strip 0..5 (columns 16w..16w+15)
    const int bc = wid & 1023;               // b*NCH + c
    const int c  = bc & (NCH - 1);
    const int b  = bc >> 3;
    const int t0 = 1 + c * CHUNK;
    const int t1 = min(SLEN, t0 + CHUNK);

    // global max of transitions (uniform scale)
    float tm = -1e30f;
    for (int k = tid; k < NTAG * NTAG; k += 64) tm = fmaxf(tm, trans[k]);
    #pragma unroll
    for (int o = 32; o > 0; o >>= 1) tm = fmaxf(tm, __shfl_xor(tm, o));
    const float tmax = tm;

    // constant A fragments = Texp^T: row j = 16*jt + b16, k i = 32*kf+8g+e
    bf16x8 Af[6][3];
    #pragma unroll
    for (int jt = 0; jt < 6; ++jt) {
        #pragma unroll
        for (int kf = 0; kf < 3; ++kf) {
            U8 u;
            #pragma unroll
            for (int d = 0; d < 4; ++d) {
                int i0 = 32 * kf + 8 * g + 2 * d;
                int j = 16 * jt + b16;
                u.u[d] = pk2bf(__expf(trans[i0 * NTAG + j] - tmax),
                               __expf(trans[(i0 + 1) * NTAG + j] - tmax));
            }
            Af[jt][kf] = u.v;
        }
    }

    // M init = identity column strip: slot tile*4+r = row j=16*tile+4g+r,
    // col i = 16*w + b16.
    float al[24];
    #pragma unroll
    for (int tile = 0; tile < 6; ++tile) {
        #pragma unroll
        for (int r = 0; r < 4; ++r)
            al[tile * 4 + r] = (16 * tile + 4 * g + r == 16 * w + b16) ? 1.0f : 0.0f;
    }
    float ls = 0.0f;

#define RENORM() do { \
    float mx_ = al[0]; \
    _Pragma("unroll") \
    for (int k_ = 1; k_ < 24; ++k_) mx_ = fmaxf(mx_, al[k_]); \
    mx_ = fmaxf(mx_, __shfl_xor(mx_, 16)); \
    mx_ = fmaxf(mx_, __shfl_xor(mx_, 32)); \
    mx_ = fmaxf(mx_, 1e-30f); \
    float inv_ = 1.0f / mx_; \
    ls += __logf(mx_); \
    _Pragma("unroll") \
    for (int k_ = 0; k_ < 24; ++k_) al[k_] *= inv_; \
} while (0)

    // pack alpha pairs -> LDS (b16-major) -> read back as B fragments.
    // write: row b16, pair q=8t+2g gets (al[4t],al[4t+1]); q+1 gets (al[4t+2],al[4t+3])
    //   => one ds_write_b64 per tile (6 total).
    // read:  Bu[kf].u[d] = row b16, pair q=16kf+4g+d (contiguous d) => 3 ds_read_b128.
    // Single wave per WG: same-wave DS ops are in-order; no barrier needed.
    U8 Bu[3];
#define MAKEB() do { \
    _Pragma("unroll") \
    for (int t_ = 0; t_ < 6; ++t_) { \
        uint2 wv_; \
        wv_.x = pk2bf(al[4 * t_ + 0], al[4 * t_ + 1]); \
        wv_.y = pk2bf(al[4 * t_ + 2], al[4 * t_ + 3]); \
        *(uint2*)(lbuf + LW * b16 + 8 * t_ + 2 * g) = wv_; \
    } \
    _Pragma("unroll") \
    for (int kf_ = 0; kf_ < 3; ++kf_) { \
        uint4 r_ = *(const uint4*)(lbuf + LW * b16 + 16 * kf_ + 4 * g); \
        Bu[kf_].u[0] = r_.x; Bu[kf_].u[1] = r_.y; \
        Bu[kf_].u[2] = r_.z; Bu[kf_].u[3] = r_.w; \
    } \
} while (0)

    MAKEB();

    const float* eB = srcE + (size_t)b * CPERB;
    const float* mkB = mask + (size_t)b * SLEN;
    const f32x4 zf4 = {0.f, 0.f, 0.f, 0.f};

    // depth-1 emission prefetch
    f32x4 Ec[6];
    #pragma unroll
    for (int tl = 0; tl < 6; ++tl)
        Ec[tl] = *(const f32x4*)(eB + (size_t)t0 * NTAG + 16 * tl + 4 * g);

    #pragma unroll 2
    for (int t = t0; t < t1; ++t) {
        const int tn = (t + 1 < t1) ? (t + 1) : t;
        f32x4 En[6];
        #pragma unroll
        for (int tl = 0; tl < 6; ++tl)
            En[tl] = *(const f32x4*)(eB + (size_t)tn * NTAG + 16 * tl + 4 * g);
        float mv = mkB[t];   // wave-uniform

        f32x4 acc[6];
        #pragma unroll
        for (int jt = 0; jt < 6; ++jt) {
            f32x4 a_ = __builtin_amdgcn_mfma_f32_16x16x32_bf16(Af[jt][0], Bu[0].v, zf4, 0, 0, 0);
            a_ = __builtin_amdgcn_mfma_f32_16x16x32_bf16(Af[jt][1], Bu[1].v, a_, 0, 0, 0);
            a_ = __builtin_amdgcn_mfma_f32_16x16x32_bf16(Af[jt][2], Bu[2].v, a_, 0, 0, 0);
            acc[jt] = a_;
        }

        if (mv != 0.0f) {
            #pragma unroll
            for (int tile = 0; tile < 6; ++tile) {
                #pragma unroll
                for (int r = 0; r < 4; ++r) {
                    float e_ = IEXP ? __expf(Ec[tile][r]) : Ec[tile][r];
                    al[tile * 4 + r] = acc[tile][r] * e_;
                }
            }
            ls += tmax;
        }
        #pragma unroll
        for (int tl = 0; tl < 6; ++tl) Ec[tl] = En[tl];
        if (((t - t0) & 7) == 7) RENORM();
        MAKEB();
    }

    // store: P[bc][i = 16w+b16][j] fp32, Pls[bc][i] per-column log-scale
    float* Pb = P + ((size_t)bc * NTAG + (16 * w + b16)) * NTAG + 4 * g;
    #pragma unroll
    for (int tile = 0; tile < 6; ++tile) {
        f32x4 v;
        v[0] = al[4 * tile + 0]; v[1] = al[4 * tile + 1];
        v[2] = al[4 * tile + 2]; v[3] = al[4 * tile + 3];
        *(f32x4*)(Pb + 16 * tile) = v;
    }
    if (tid < 16) Pls[(size_t)bc * NTAG + 16 * w + b16] = ls;
#undef MAKEB
#undef RENORM
}

// ---------------------------------------------------------------------------
// Phase 2: per-batch log-domain fold of the NCH chunk operators.
// ---------------------------------------------------------------------------
__global__ __launch_bounds__(128) void crf_fold(
    const float* __restrict__ em, const float* __restrict__ startT,
    const float* __restrict__ endT,
    const float* __restrict__ P, const float* __restrict__ Pls,
    float* __restrict__ den)
{
    __shared__ float aS[NTAG];
    __shared__ float sRed[2];
    const int b = blockIdx.x, tid = threadIdx.x;
    const bool act = tid < NTAG;

    float A = act ? (startT[tid] + em[(size_t)b * CPERB + tid]) : -1e30f;

    for (int c = 0; c < NCH; ++c) {
        const size_t bc = (size_t)b * NCH + c;
        float v = act ? (A + Pls[bc * NTAG + tid]) : -1e30f;
        float mv = v;
        #pragma unroll
        for (int o = 32; o > 0; o >>= 1) mv = fmaxf(mv, __shfl_xor(mv, o));
        if ((tid & 63) == 0) sRed[tid >> 6] = mv;
        __syncthreads();
        const float m = fmaxf(sRed[0], sRed[1]);
        __syncthreads();
        if (act) aS[tid] = __expf(v - m);
        __syncthreads();
        if (act) {
            const float* Pc = P + bc * (NTAG * NTAG) + tid;
            float dot = 0.f;
            #pragma unroll 8
            for (int i = 0; i < NTAG; ++i)
                dot = fmaf(aS[i], Pc[(size_t)i * NTAG], dot);
            A = m + __logf(dot);
        }
        __syncthreads();
    }

    float Afin = act ? (A + endT[tid]) : -1e30f;
    float mv = Afin;
    #pragma unroll
    for (int o = 32; o > 0; o >>= 1) mv = fmaxf(mv, __shfl_xor(mv, o));
    if ((tid & 63) == 0) sRed[tid >> 6] = mv;
    __syncthreads();
    const float m2 = fmaxf(sRed[0], sRed[1]);
    __syncthreads();
    float ex = act ? __expf(Afin - m2) : 0.f;
    ex = waveSum(ex);
    if ((tid & 63) == 0) sRed[tid >> 6] = ex;
    __syncthreads();
    if (tid == 0) den[b] = m2 + __logf(sRed[0] + sRed[1]);
}

// ---------------------------------------------------------------------------
// Fallback sequential forward (R3-verified structure) — only if ws too small.
// ---------------------------------------------------------------------------
__global__ __launch_bounds__(64, 1) void crf_forward_seq(
    const float* __restrict__ srcE, const float* __restrict__ srcM,
    const float* __restrict__ trans, const float* __restrict__ startT,
    const float* __restrict__ endT, float* __restrict__ den)
{
    __shared__ unsigned int lbuf[2][48 * 20];
    const int tid = threadIdx.x;
    const int g = tid >> 4;
    const int b16 = tid & 15;
    const int b = blockIdx.x * 16 + b16;

    float tm = -1e30f;
    for (int k = tid; k < NTAG * NTAG; k += 64) tm = fmaxf(tm, trans[k]);
    #pragma unroll
    for (int o = 32; o > 0; o >>= 1) tm = fmaxf(tm, __shfl_xor(tm, o));
    const float tmax = tm;

    bf16x8 Af[6][3];
    #pragma unroll
    for (int jt = 0; jt < 6; ++jt) {
        #pragma unroll
        for (int kf = 0; kf < 3; ++kf) {
            U8 u;
            #pragma unroll
            for (int d = 0; d < 4; ++d) {
                int i0 = 32 * kf + 8 * g + 2 * d;
                int j = 16 * jt + b16;
                u.u[d] = pk2bf(__expf(trans[i0 * NTAG + j] - tmax),
                               __expf(trans[(i0 + 1) * NTAG + j] - tmax));
            }
            Af[jt][kf] = u.v;
        }
    }

    float al[24];
    #pragma unroll
    for (int tile = 0; tile < 6; ++tile) {
        #pragma unroll
        for (int r = 0; r < 4; ++r) {
            int j = 16 * tile + 4 * g + r;
            al[tile * 4 + r] = __expf(startT[j]) * __expf(srcE[(size_t)b * CPERB + j]);
        }
    }
    float ls = 0.0f;

#define RENORM2() do { \
    float mx_ = al[0]; \
    _Pragma("unroll") \
    for (int k_ = 1; k_ < 24; ++k_) mx_ = fmaxf(mx_, al[k_]); \
    mx_ = fmaxf(mx_, __shfl_xor(mx_, 16)); \
    mx_ = fmaxf(mx_, __shfl_xor(mx_, 32)); \
    mx_ = fmaxf(mx_, 1e-30f); \
    float inv_ = 1.0f / mx_; \
    ls += __logf(mx_); \
    _Pragma("unroll") \
    for (int k_ = 0; k_ < 24; ++k_) al[k_] *= inv_; \
} while (0)

    U8 Bu[3];
#define MAKEB2(BUF) do { \
    _Pragma("unroll") \
    for (int t_ = 0; t_ < 6; ++t_) { \
        lbuf[BUF][(8 * t_ + 2 * g) * 20 + b16]     = pk2bf(al[4 * t_ + 0], al[4 * t_ + 1]); \
        lbuf[BUF][(8 * t_ + 2 * g + 1) * 20 + b16] = pk2bf(al[4 * t_ + 2], al[4 * t_ + 3]); \
    } \
    __syncthreads(); \
    _Pragma("unroll") \
    for (int kf_ = 0; kf_ < 3; ++kf_) { \
        _Pragma("unroll") \
        for (int d_ = 0; d_ < 4; ++d_) \
            Bu[kf_].u[d_] = lbuf[BUF][(16 * kf_ + 4 * g + d_) * 20 + b16]; \
    } \
} while (0)

    RENORM2();
    MAKEB2(0);
    const f32x4 zf4 = {0.f, 0.f, 0.f, 0.f};

    #pragma unroll 1
    for (int t = 1; t < SLEN; ++t) {
        f32x4 E[6];
        #pragma unroll
        for (int tl = 0; tl < 6; ++tl)
            E[tl] = *(const f32x4*)(srcE + (size_t)b * CPERB + (size_t)t * NTAG + 16 * tl + 4 * g);
        float mv = srcM[(size_t)b * SLEN + t];
        f32x4 acc[6];
        #pragma unroll
        for (int jt = 0; jt < 6; ++jt) {
            f32x4 a_ = __builtin_amdgcn_mfma_f32_16x16x32_bf16(Af[jt][0], Bu[0].v, zf4, 0, 0, 0);
            a_ = __builtin_amdgcn_mfma_f32_16x16x32_bf16(Af[jt][1], Bu[1].v, a_, 0, 0, 0);
            a_ = __builtin_amdgcn_mfma_f32_16x16x32_bf16(Af[jt][2], Bu[2].v, a_, 0, 0, 0);
            acc[jt] = a_;
        }
        bool km = (mv != 0.0f);
        #pragma unroll
        for (int tile = 0; tile < 6; ++tile) {
            #pragma unroll
            for (int r = 0; r < 4; ++r) {
                float nv = acc[tile][r] * __expf(E[tile][r]);
                al[tile * 4 + r] = km ? nv : al[tile * 4 + r];
            }
        }
        ls += km ? tmax : 0.0f;
        if ((t & 3) == 0) RENORM2();
        MAKEB2(t & 1);
        __syncthreads();
    }

    float s = 0.f;
    #pragma unroll
    for (int tile = 0; tile < 6; ++tile) {
        #pragma unroll
        for (int r = 0; r < 4; ++r) {
            int j = 16 * tile + 4 * g + r;
            s += al[tile * 4 + r] * __expf(endT[j]);
        }
    }
    s += __shfl_xor(s, 16);
    s += __shfl_xor(s, 32);
    if (tid < 16) den[b] = ls + __logf(s);
#undef MAKEB2
#undef RENORM2
}

// ---------------------------------------------------------------------------
// Gold-path score (verified, unchanged)
// ---------------------------------------------------------------------------
__global__ __launch_bounds__(256) void crf_score(
    const float* __restrict__ em, const int* __restrict__ tags,
    const float* __restrict__ mask, const float* __restrict__ trans,
    const float* __restrict__ startT, const float* __restrict__ endT,
    float* __restrict__ num)
{
    __shared__ float sS[4], sM[4];
    const int b = blockIdx.x, tid = threadIdx.x;
    const float* emB = em + (size_t)b * CPERB;
    const int* tgB = tags + (size_t)b * SLEN;
    const float* mkB = mask + (size_t)b * SLEN;

    float part = 0.f, mcnt = 0.f;
    for (int t = tid; t < SLEN; t += 256) {
        float mt = mkB[t];
        mcnt += mt;
        if (t >= 1) {
            int tp = tgB[t - 1], tc = tgB[t];
            part += (trans[tp * NTAG + tc] + emB[(size_t)t * NTAG + tc]) * mt;
        }
    }
    part = waveSum(part);
    mcnt = waveSum(mcnt);
    if ((tid & 63) == 0) { sS[tid >> 6] = part; sM[tid >> 6] = mcnt; }
    __syncthreads();
    if (tid == 0) {
        float tot = sS[0] + sS[1] + sS[2] + sS[3];
        int last = (int)(sM[0] + sM[1] + sM[2] + sM[3]) - 1;
        int t0 = tgB[0];
        num[b] = tot + startT[t0] + emB[t0] + endT[tgB[last]];
    }
}

__global__ __launch_bounds__(128) void crf_final(
    const float* __restrict__ den, const float* __restrict__ num,
    float* __restrict__ out)
{
    __shared__ float s2[2];
    const int tid = threadIdx.x;
    float v = den[tid] - num[tid];
    v = waveSum(v);
    if ((tid & 63) == 0) s2[tid >> 6] = v;
    __syncthreads();
    if (tid == 0) out[0] = (s2[0] + s2[1]) * (1.0f / NB);
}

extern "C" void kernel_launch(void* const* d_in, const int* in_sizes, int n_in,
                              void* d_out, int out_size, void* d_ws, size_t ws_size,
                              hipStream_t stream) {
    const float* em     = (const float*)d_in[0];
    const int*   tags   = (const int*)d_in[1];
    const float* mask   = (const float*)d_in[2];
    const float* trans  = (const float*)d_in[3];
    const float* startT = (const float*)d_in[4];
    const float* endT   = (const float*)d_in[5];
    float* out = (float*)d_out;
    float* num = (float*)d_ws;                        // [128]
    float* den = num + NB;                            // [128]

    const size_t szP   = (size_t)NB * NCH * NTAG * NTAG;   // floats
    const size_t szPls = (size_t)NB * NCH * NTAG;
    float* P    = (float*)((char*)d_ws + 4096);
    float* Pls  = P + szP;
    float* eexp = Pls + szPls;
    const size_t need_mid  = 4096 + (szP + szPls) * 4;
    const size_t need_full = need_mid + (size_t)NB * CPERB * 4;

    crf_score<<<NB, 256, 0, stream>>>(em, tags, mask, trans, startT, endT, num);
    if (ws_size >= need_full) {
        exp_pass<<<(NB * CPERB) / (256 * 4), 256, 0, stream>>>(em, eexp);
        crf_chunk<0><<<6 * NB * NCH, 64, 0, stream>>>(eexp, mask, trans, P, Pls);
        crf_fold<<<NB, 128, 0, stream>>>(em, startT, endT, P, Pls, den);
    } else if (ws_size >= need_mid) {
        crf_chunk<1><<<6 * NB * NCH, 64, 0, stream>>>(em, mask, trans, P, Pls);
        crf_fold<<<NB, 128, 0, stream>>>(em, startT, endT, P, Pls, den);
    } else {
        crf_forward_seq<<<NB / 16, 64, 0, stream>>>(em, mask, trans, startT, endT, den);
    }
    crf_final<<<1, 128, 0, stream>>>(den, num, out);
}

// Round 7
// 672.859 us; speedup vs baseline: 6.0543x; 6.0543x over previous
//
#include <hip/hip_runtime.h>
#include <hip/hip_bf16.h>
#include <math.h>

#define NTAG 96
#define NB   128
#define SLEN 2048
#define CPERB (SLEN * NTAG)     // floats per batch row of em
#define NCH  8                  // chunks per sequence
#define CHUNK 256               // steps per chunk

#if defined(__has_builtin)
#if __has_builtin(__builtin_amdgcn_mfma_f32_16x16x16bf16_1k)
#define HAVE_K16 1
#endif
#endif
#ifndef HAVE_K16
#define HAVE_K16 0
#endif

typedef __attribute__((ext_vector_type(8))) short bf16x8;
typedef __attribute__((ext_vector_type(4))) short bf16x4;
typedef __attribute__((ext_vector_type(4))) float f32x4;
union U8 { unsigned int u[4]; bf16x8 v; };
union U4 { unsigned int u[2]; bf16x4 v; };

__device__ __forceinline__ unsigned int pk2bf(float lo, float hi) {
    union { __hip_bfloat16 h; unsigned short u; } a, b;
    a.h = __float2bfloat16(lo);
    b.h = __float2bfloat16(hi);
    return (unsigned int)a.u | ((unsigned int)b.u << 16);
}

__device__ __forceinline__ float waveSum(float v) {
    #pragma unroll
    for (int o = 32; o > 0; o >>= 1) v += __shfl_xor(v, o);
    return v;
}

// ---------------------------------------------------------------------------
// exp_pass: eexp[i] = exp(em[i]) elementwise, layout preserved. Memory-bound.
// ---------------------------------------------------------------------------
__global__ __launch_bounds__(256) void exp_pass(
    const float* __restrict__ x, float* __restrict__ y)
{
    size_t i = (size_t)blockIdx.x * 256 + threadIdx.x;   // one f32x4 each
    f32x4 v = ((const f32x4*)x)[i];
    f32x4 o;
    o[0] = __expf(v[0]); o[1] = __expf(v[1]);
    o[2] = __expf(v[2]); o[3] = __expf(v[3]);
    ((f32x4*)y)[i] = o;
}

// ---------------------------------------------------------------------------
// Phase 1: per (batch, chunk, strip) wave computes a 96x16 column-strip of
// the chunk operator product  M <- diag(e_t) * Texp^T * M,  M init = Identity.
// K16 path: mfma 16x16x16 -> B-fragment granularity (4 k/lane) == C-output
// granularity (4 rows/lane): relayout is LANE-LOCAL (no LDS/shfl/barrier).
// Fallback: R4-verified K=32 + LDS MAKEB.
// IEXP=1: srcE raw em (exp inline). IEXP=0: srcE = eexp.
// ---------------------------------------------------------------------------
template <int IEXP>
__global__ __launch_bounds__(64, 2) void crf_chunk(
    const float* __restrict__ srcE, const float* __restrict__ mask,
    const float* __restrict__ trans,
    float* __restrict__ P, float* __restrict__ Pls)
{
#if !HAVE_K16
    __shared__ unsigned int lbuf[48 * 20];
#endif
    const int tid = threadIdx.x;
    const int g = tid >> 4, b16 = tid & 15;

    // XCD-bijective decode: the 6 strips of one (b,c) are dispatch-adjacent
    // on the same XCD (shared emission stream -> L2 reuse).
    const int k   = blockIdx.x;          // 0..6143
    const int xcd = k & 7;
    const int seq = k >> 3;              // 0..767
    const int w   = seq % 6;             // strip: columns 16w..16w+15
    const int bcg = seq / 6;             // 0..127
    const int bc  = bcg * 8 + xcd;       // b*NCH + c
    const int c   = bc & (NCH - 1);
    const int b   = bc >> 3;
    const int t0  = 1 + c * CHUNK;
    const int t1  = min(SLEN, t0 + CHUNK);

    // global max of transitions (uniform scale)
    float tm = -1e30f;
    for (int q = tid; q < NTAG * NTAG; q += 64) tm = fmaxf(tm, trans[q]);
    #pragma unroll
    for (int o = 32; o > 0; o >>= 1) tm = fmaxf(tm, __shfl_xor(tm, o));
    const float tmax = tm;

#if HAVE_K16
    // A frags (K=16, 6 segments): row j=16jt+b16, k i = 16s+4g+e (e=0..3)
    U4 Af16[6][6];
    #pragma unroll
    for (int jt = 0; jt < 6; ++jt) {
        #pragma unroll
        for (int s = 0; s < 6; ++s) {
            #pragma unroll
            for (int d = 0; d < 2; ++d) {
                int i0 = 16 * s + 4 * g + 2 * d;
                int j = 16 * jt + b16;
                Af16[jt][s].u[d] = pk2bf(__expf(trans[i0 * NTAG + j] - tmax),
                                         __expf(trans[(i0 + 1) * NTAG + j] - tmax));
            }
        }
    }
#else
    // A frags (K=32, 3 segments): row j=16jt+b16, k i = 32kf+8g+e (e=0..7)
    bf16x8 Af[6][3];
    #pragma unroll
    for (int jt = 0; jt < 6; ++jt) {
        #pragma unroll
        for (int kf = 0; kf < 3; ++kf) {
            U8 u;
            #pragma unroll
            for (int d = 0; d < 4; ++d) {
                int i0 = 32 * kf + 8 * g + 2 * d;
                int j = 16 * jt + b16;
                u.u[d] = pk2bf(__expf(trans[i0 * NTAG + j] - tmax),
                               __expf(trans[(i0 + 1) * NTAG + j] - tmax));
            }
            Af[jt][kf] = u.v;
        }
    }
#endif

    // M init = identity column strip: slot tile*4+r = row j=16*tile+4g+r,
    // col i = 16*w + b16.
    float al[24];
    #pragma unroll
    for (int tile = 0; tile < 6; ++tile) {
        #pragma unroll
        for (int r = 0; r < 4; ++r)
            al[tile * 4 + r] = (16 * tile + 4 * g + r == 16 * w + b16) ? 1.0f : 0.0f;
    }
    float ls = 0.0f;

#define RENORM() do { \
    float mx_ = al[0]; \
    _Pragma("unroll") \
    for (int k_ = 1; k_ < 24; ++k_) mx_ = fmaxf(mx_, al[k_]); \
    mx_ = fmaxf(mx_, __shfl_xor(mx_, 16)); \
    mx_ = fmaxf(mx_, __shfl_xor(mx_, 32)); \
    mx_ = fmaxf(mx_, 1e-30f); \
    float inv_ = 1.0f / mx_; \
    ls += __logf(mx_); \
    _Pragma("unroll") \
    for (int k_ = 0; k_ < 24; ++k_) al[k_] *= inv_; \
} while (0)

#if HAVE_K16
    // B frag for segment s: k = 16s+4g+e == row of al slot 4s+e. Lane-local.
    U4 Bu16[6];
#define MAKEB() do { \
    _Pragma("unroll") \
    for (int s_ = 0; s_ < 6; ++s_) { \
        Bu16[s_].u[0] = pk2bf(al[4 * s_ + 0], al[4 * s_ + 1]); \
        Bu16[s_].u[1] = pk2bf(al[4 * s_ + 2], al[4 * s_ + 3]); \
    } \
} while (0)
#define MFMABLOCK(ACC) do { \
    _Pragma("unroll") \
    for (int jt_ = 0; jt_ < 6; ++jt_) ACC[jt_] = zf4; \
    _Pragma("unroll") \
    for (int s_ = 0; s_ < 6; ++s_) { \
        _Pragma("unroll") \
        for (int jt_ = 0; jt_ < 6; ++jt_) \
            ACC[jt_] = __builtin_amdgcn_mfma_f32_16x16x16bf16_1k( \
                Af16[jt_][s_].v, Bu16[s_].v, ACC[jt_], 0, 0, 0); \
    } \
} while (0)
#else
    // R4-verified LDS relayout: write pairs q=8t+2g(+1) row-major [48][20],
    // barrier, read pairs q=16kf+4g+d, barrier.
    U8 Bu[3];
#define MAKEB() do { \
    _Pragma("unroll") \
    for (int t_ = 0; t_ < 6; ++t_) { \
        lbuf[(8 * t_ + 2 * g) * 20 + b16]     = pk2bf(al[4 * t_ + 0], al[4 * t_ + 1]); \
        lbuf[(8 * t_ + 2 * g + 1) * 20 + b16] = pk2bf(al[4 * t_ + 2], al[4 * t_ + 3]); \
    } \
    __syncthreads(); \
    _Pragma("unroll") \
    for (int kf_ = 0; kf_ < 3; ++kf_) { \
        _Pragma("unroll") \
        for (int d_ = 0; d_ < 4; ++d_) \
            Bu[kf_].u[d_] = lbuf[(16 * kf_ + 4 * g + d_) * 20 + b16]; \
    } \
    __syncthreads(); \
} while (0)
#define MFMABLOCK(ACC) do { \
    _Pragma("unroll") \
    for (int jt_ = 0; jt_ < 6; ++jt_) { \
        f32x4 a_ = __builtin_amdgcn_mfma_f32_16x16x32_bf16(Af[jt_][0], Bu[0].v, zf4, 0, 0, 0); \
        a_ = __builtin_amdgcn_mfma_f32_16x16x32_bf16(Af[jt_][1], Bu[1].v, a_, 0, 0, 0); \
        a_ = __builtin_amdgcn_mfma_f32_16x16x32_bf16(Af[jt_][2], Bu[2].v, a_, 0, 0, 0); \
        ACC[jt_] = a_; \
    } \
} while (0)
#endif

    const float* eB  = srcE + (size_t)b * CPERB;
    const float* mkB = mask + (size_t)b * SLEN;
    const f32x4 zf4 = {0.f, 0.f, 0.f, 0.f};

    f32x4 E0[6], E1[6];
#define LOADE(EN, T) do { \
    int tn_ = (T) < t1 ? (T) : (t1 - 1); \
    _Pragma("unroll") \
    for (int tl_ = 0; tl_ < 6; ++tl_) \
        EN[tl_] = *(const f32x4*)(eB + (size_t)tn_ * NTAG + 16 * tl_ + 4 * g); \
} while (0)

    // STEP: prefetch em[T+1] into EN; mfma with current Bu (state at T-1);
    // al <- acc * e_T if mask. NOTE: MAKEB is called by the LOOP, after any
    // RENORM (ordering is load-bearing: Bu must reflect renormalized al).
#define STEP(EC, EN, T) do { \
    LOADE(EN, (T) + 1); \
    float mv_ = mkB[(T)]; \
    f32x4 acc_[6]; \
    MFMABLOCK(acc_); \
    if (mv_ != 0.0f) { \
        _Pragma("unroll") \
        for (int tile_ = 0; tile_ < 6; ++tile_) { \
            _Pragma("unroll") \
            for (int r_ = 0; r_ < 4; ++r_) { \
                float e_ = IEXP ? __expf(EC[tile_][r_]) : EC[tile_][r_]; \
                al[tile_ * 4 + r_] = acc_[tile_][r_] * e_; \
            } \
        } \
        ls += tmax; \
    } \
} while (0)

    MAKEB();
    LOADE(E0, t0);

    const int nsteps = t1 - t0;        // 256 (or 255 for last chunk)
    const int nfull  = nsteps >> 2;    // blocks of 4 steps
    int t = t0;
    #pragma unroll 1
    for (int blk = 0; blk < nfull; ++blk, t += 4) {
        STEP(E0, E1, t + 0);           MAKEB();
        STEP(E1, E0, t + 1);           MAKEB();
        STEP(E0, E1, t + 2);           MAKEB();
        STEP(E1, E0, t + 3); RENORM(); MAKEB();
    }
    // tail (<=3 steps), renorm each to keep al/ls consistent
    if (t < t1) { STEP(E0, E1, t); RENORM(); MAKEB(); ++t; }
    if (t < t1) { STEP(E1, E0, t); RENORM(); MAKEB(); ++t; }
    if (t < t1) { STEP(E0, E1, t); RENORM(); MAKEB(); ++t; }

    // store: P[bc][i = 16w+b16][j] fp32, Pls[bc][i] per-column log-scale
    float* Pb = P + ((size_t)bc * NTAG + (16 * w + b16)) * NTAG + 4 * g;
    #pragma unroll
    for (int tile = 0; tile < 6; ++tile) {
        f32x4 v;
        v[0] = al[4 * tile + 0]; v[1] = al[4 * tile + 1];
        v[2] = al[4 * tile + 2]; v[3] = al[4 * tile + 3];
        *(f32x4*)(Pb + 16 * tile) = v;
    }
    if (tid < 16) Pls[(size_t)bc * NTAG + 16 * w + b16] = ls;
#undef STEP
#undef LOADE
#undef MAKEB
#undef MFMABLOCK
#undef RENORM
}

// ---------------------------------------------------------------------------
// Phase 2: per-batch log-domain fold of the NCH chunk operators. (verified)
// ---------------------------------------------------------------------------
__global__ __launch_bounds__(128) void crf_fold(
    const float* __restrict__ em, const float* __restrict__ startT,
    const float* __restrict__ endT,
    const float* __restrict__ P, const float* __restrict__ Pls,
    float* __restrict__ den)
{
    __shared__ float aS[NTAG];
    __shared__ float sRed[2];
    const int b = blockIdx.x, tid = threadIdx.x;
    const bool act = tid < NTAG;

    float A = act ? (startT[tid] + em[(size_t)b * CPERB + tid]) : -1e30f;

    for (int c = 0; c < NCH; ++c) {
        const size_t bc = (size_t)b * NCH + c;
        float v = act ? (A + Pls[bc * NTAG + tid]) : -1e30f;
        float mv = v;
        #pragma unroll
        for (int o = 32; o > 0; o >>= 1) mv = fmaxf(mv, __shfl_xor(mv, o));
        if ((tid & 63) == 0) sRed[tid >> 6] = mv;
        __syncthreads();
        const float m = fmaxf(sRed[0], sRed[1]);
        __syncthreads();
        if (act) aS[tid] = __expf(v - m);
        __syncthreads();
        if (act) {
            const float* Pc = P + bc * (NTAG * NTAG) + tid;
            float dot = 0.f;
            #pragma unroll 8
            for (int i = 0; i < NTAG; ++i)
                dot = fmaf(aS[i], Pc[(size_t)i * NTAG], dot);
            A = m + __logf(dot);
        }
        __syncthreads();
    }

    float Afin = act ? (A + endT[tid]) : -1e30f;
    float mv = Afin;
    #pragma unroll
    for (int o = 32; o > 0; o >>= 1) mv = fmaxf(mv, __shfl_xor(mv, o));
    if ((tid & 63) == 0) sRed[tid >> 6] = mv;
    __syncthreads();
    const float m2 = fmaxf(sRed[0], sRed[1]);
    __syncthreads();
    float ex = act ? __expf(Afin - m2) : 0.f;
    ex = waveSum(ex);
    if ((tid & 63) == 0) sRed[tid >> 6] = ex;
    __syncthreads();
    if (tid == 0) den[b] = m2 + __logf(sRed[0] + sRed[1]);
}

// ---------------------------------------------------------------------------
// Fallback sequential forward (R3-verified structure) — only if ws too small.
// ---------------------------------------------------------------------------
__global__ __launch_bounds__(64, 1) void crf_forward_seq(
    const float* __restrict__ srcE, const float* __restrict__ srcM,
    const float* __restrict__ trans, const float* __restrict__ startT,
    const float* __restrict__ endT, float* __restrict__ den)
{
    __shared__ unsigned int lbuf[2][48 * 20];
    const int tid = threadIdx.x;
    const int g = tid >> 4;
    const int b16 = tid & 15;
    const int b = blockIdx.x * 16 + b16;

    float tm = -1e30f;
    for (int q = tid; q < NTAG * NTAG; q += 64) tm = fmaxf(tm, trans[q]);
    #pragma unroll
    for (int o = 32; o > 0; o >>= 1) tm = fmaxf(tm, __shfl_xor(tm, o));
    const float tmax = tm;

    bf16x8 Af[6][3];
    #pragma unroll
    for (int jt = 0; jt < 6; ++jt) {
        #pragma unroll
        for (int kf = 0; kf < 3; ++kf) {
            U8 u;
            #pragma unroll
            for (int d = 0; d < 4; ++d) {
                int i0 = 32 * kf + 8 * g + 2 * d;
                int j = 16 * jt + b16;
                u.u[d] = pk2bf(__expf(trans[i0 * NTAG + j] - tmax),
                               __expf(trans[(i0 + 1) * NTAG + j] - tmax));
            }
            Af[jt][kf] = u.v;
        }
    }

    float al[24];
    #pragma unroll
    for (int tile = 0; tile < 6; ++tile) {
        #pragma unroll
        for (int r = 0; r < 4; ++r) {
            int j = 16 * tile + 4 * g + r;
            al[tile * 4 + r] = __expf(startT[j]) * __expf(srcE[(size_t)b * CPERB + j]);
        }
    }
    float ls = 0.0f;

#define RENORM2() do { \
    float mx_ = al[0]; \
    _Pragma("unroll") \
    for (int k_ = 1; k_ < 24; ++k_) mx_ = fmaxf(mx_, al[k_]); \
    mx_ = fmaxf(mx_, __shfl_xor(mx_, 16)); \
    mx_ = fmaxf(mx_, __shfl_xor(mx_, 32)); \
    mx_ = fmaxf(mx_, 1e-30f); \
    float inv_ = 1.0f / mx_; \
    ls += __logf(mx_); \
    _Pragma("unroll") \
    for (int k_ = 0; k_ < 24; ++k_) al[k_] *= inv_; \
} while (0)

    U8 Bu[3];
#define MAKEB2(BUF) do { \
    _Pragma("unroll") \
    for (int t_ = 0; t_ < 6; ++t_) { \
        lbuf[BUF][(8 * t_ + 2 * g) * 20 + b16]     = pk2bf(al[4 * t_ + 0], al[4 * t_ + 1]); \
        lbuf[BUF][(8 * t_ + 2 * g + 1) * 20 + b16] = pk2bf(al[4 * t_ + 2], al[4 * t_ + 3]); \
    } \
    __syncthreads(); \
    _Pragma("unroll") \
    for (int kf_ = 0; kf_ < 3; ++kf_) { \
        _Pragma("unroll") \
        for (int d_ = 0; d_ < 4; ++d_) \
            Bu[kf_].u[d_] = lbuf[BUF][(16 * kf_ + 4 * g + d_) * 20 + b16]; \
    } \
} while (0)

    RENORM2();
    MAKEB2(0);
    const f32x4 zf4 = {0.f, 0.f, 0.f, 0.f};

    #pragma unroll 1
    for (int t = 1; t < SLEN; ++t) {
        f32x4 E[6];
        #pragma unroll
        for (int tl = 0; tl < 6; ++tl)
            E[tl] = *(const f32x4*)(srcE + (size_t)b * CPERB + (size_t)t * NTAG + 16 * tl + 4 * g);
        float mv = srcM[(size_t)b * SLEN + t];
        f32x4 acc[6];
        #pragma unroll
        for (int jt = 0; jt < 6; ++jt) {
            f32x4 a_ = __builtin_amdgcn_mfma_f32_16x16x32_bf16(Af[jt][0], Bu[0].v, zf4, 0, 0, 0);
            a_ = __builtin_amdgcn_mfma_f32_16x16x32_bf16(Af[jt][1], Bu[1].v, a_, 0, 0, 0);
            a_ = __builtin_amdgcn_mfma_f32_16x16x32_bf16(Af[jt][2], Bu[2].v, a_, 0, 0, 0);
            acc[jt] = a_;
        }
        bool km = (mv != 0.0f);
        #pragma unroll
        for (int tile = 0; tile < 6; ++tile) {
            #pragma unroll
            for (int r = 0; r < 4; ++r) {
                float nv = acc[tile][r] * __expf(E[tile][r]);
                al[tile * 4 + r] = km ? nv : al[tile * 4 + r];
            }
        }
        ls += km ? tmax : 0.0f;
        if ((t & 3) == 0) RENORM2();
        MAKEB2(t & 1);
        __syncthreads();
    }

    float s = 0.f;
    #pragma unroll
    for (int tile = 0; tile < 6; ++tile) {
        #pragma unroll
        for (int r = 0; r < 4; ++r) {
            int j = 16 * tile + 4 * g + r;
            s += al[tile * 4 + r] * __expf(endT[j]);
        }
    }
    s += __shfl_xor(s, 16);
    s += __shfl_xor(s, 32);
    if (tid < 16) den[b] = ls + __logf(s);
#undef MAKEB2
#undef RENORM2
}

// ---------------------------------------------------------------------------
// Gold-path score (verified, unchanged)
// ---------------------------------------------------------------------------
__global__ __launch_bounds__(256) void crf_score(
    const float* __restrict__ em, const int* __restrict__ tags,
    const float* __restrict__ mask, const float* __restrict__ trans,
    const float* __restrict__ startT, const float* __restrict__ endT,
    float* __restrict__ num)
{
    __shared__ float sS[4], sM[4];
    const int b = blockIdx.x, tid = threadIdx.x;
    const float* emB = em + (size_t)b * CPERB;
    const int* tgB = tags + (size_t)b * SLEN;
    const float* mkB = mask + (size_t)b * SLEN;

    float part = 0.f, mcnt = 0.f;
    for (int t = tid; t < SLEN; t += 256) {
        float mt = mkB[t];
        mcnt += mt;
        if (t >= 1) {
            int tp = tgB[t - 1], tc = tgB[t];
            part += (trans[tp * NTAG + tc] + emB[(size_t)t * NTAG + tc]) * mt;
        }
    }
    part = waveSum(part);
    mcnt = waveSum(mcnt);
    if ((tid & 63) == 0) { sS[tid >> 6] = part; sM[tid >> 6] = mcnt; }
    __syncthreads();
    if (tid == 0) {
        float tot = sS[0] + sS[1] + sS[2] + sS[3];
        int last = (int)(sM[0] + sM[1] + sM[2] + sM[3]) - 1;
        int t0 = tgB[0];
        num[b] = tot + startT[t0] + emB[t0] + endT[tgB[last]];
    }
}

__global__ __launch_bounds__(128) void crf_final(
    const float* __restrict__ den, const float* __restrict__ num,
    float* __restrict__ out)
{
    __shared__ float s2[2];
    const int tid = threadIdx.x;
    float v = den[tid] - num[tid];
    v = waveSum(v);
    if ((tid & 63) == 0) s2[tid >> 6] = v;
    __syncthreads();
    if (tid == 0) out[0] = (s2[0] + s2[1]) * (1.0f / NB);
}

extern "C" void kernel_launch(void* const* d_in, const int* in_sizes, int n_in,
                              void* d_out, int out_size, void* d_ws, size_t ws_size,
                              hipStream_t stream) {
    const float* em     = (const float*)d_in[0];
    const int*   tags   = (const int*)d_in[1];
    const float* mask   = (const float*)d_in[2];
    const float* trans  = (const float*)d_in[3];
    const float* startT = (const float*)d_in[4];
    const float* endT   = (const float*)d_in[5];
    float* out = (float*)d_out;
    float* num = (float*)d_ws;                        // [128]
    float* den = num + NB;                            // [128]

    const size_t szP   = (size_t)NB * NCH * NTAG * NTAG;   // floats
    const size_t szPls = (size_t)NB * NCH * NTAG;
    float* P    = (float*)((char*)d_ws + 4096);
    float* Pls  = P + szP;
    float* eexp = Pls + szPls;
    const size_t need_mid  = 4096 + (szP + szPls) * 4;
    const size_t need_full = need_mid + (size_t)NB * CPERB * 4;

    crf_score<<<NB, 256, 0, stream>>>(em, tags, mask, trans, startT, endT, num);
    if (ws_size >= need_full) {
        exp_pass<<<(NB * CPERB) / (256 * 4), 256, 0, stream>>>(em, eexp);
        crf_chunk<0><<<6 * NB * NCH, 64, 0, stream>>>(eexp, mask, trans, P, Pls);
        crf_fold<<<NB, 128, 0, stream>>>(em, startT, endT, P, Pls, den);
    } else if (ws_size >= need_mid) {
        crf_chunk<1><<<6 * NB * NCH, 64, 0, stream>>>(em, mask, trans, P, Pls);
        crf_fold<<<NB, 128, 0, stream>>>(em, startT, endT, P, Pls, den);
    } else {
        crf_forward_seq<<<NB / 16, 64, 0, stream>>>(em, mask, trans, startT, endT, den);
    }
    crf_final<<<1, 128, 0, stream>>>(den, num, out);
}